// Round 9
// baseline (477.507 us; speedup 1.0000x reference)
//
#include <hip/hip_runtime.h>
#include <math.h>

#define LEVELS 16
#define MAX_RES 2048
#define NCELL_BITS 5
#define NCELLS (1 << (3 * NCELL_BITS))   // 32768 cells (32^3), ~32 points/cell

typedef float nfloat4 __attribute__((ext_vector_type(4)));

struct ResParams { int res[LEVELS]; float mul[LEVELS]; int mulmask; };

// ---------------- sort pipeline ----------------

__global__ __launch_bounds__(256) void zero_hist(unsigned int* hist) {
  int i = blockIdx.x * 256 + threadIdx.x;
  if (i < NCELLS) hist[i] = 0u;
}

__device__ __forceinline__ unsigned int morton5(int cx, int cy, int cz) {
  unsigned int k = 0;
  #pragma unroll
  for (int b = 0; b < NCELL_BITS; ++b)
    k |= (((cx >> b) & 1) << (3 * b)) | (((cy >> b) & 1) << (3 * b + 1)) |
         (((cz >> b) & 1) << (3 * b + 2));
  return k;
}

__device__ __forceinline__ unsigned int cell_of(float x, float y, float z) {
  int cx = min(31, max(0, (int)(x * 32.0f)));
  int cy = min(31, max(0, (int)(y * 32.0f)));
  int cz = min(31, max(0, (int)(z * 32.0f)));
  return morton5(cx, cy, cz);
}

__global__ __launch_bounds__(256) void keys_hist(const float* __restrict__ pos,
                                                 unsigned int* __restrict__ hist, int B) {
  int i = blockIdx.x * 256 + threadIdx.x;
  if (i >= B) return;
  atomicAdd(&hist[cell_of(pos[i*3], pos[i*3+1], pos[i*3+2])], 1u);
}

__global__ __launch_bounds__(1024) void scan_kernel(const unsigned int* __restrict__ hist,
                                                    unsigned int* __restrict__ offs) {
  __shared__ unsigned int part[1024];
  const int SEG = NCELLS / 1024;          // 32
  int t = threadIdx.x;
  int base = t * SEG;
  unsigned int s = 0;
  #pragma unroll
  for (int j = 0; j < SEG; ++j) s += hist[base + j];
  part[t] = s;
  __syncthreads();
  for (int off = 1; off < 1024; off <<= 1) {
    unsigned int v = (t >= off) ? part[t - off] : 0u;
    __syncthreads();
    part[t] += v;
    __syncthreads();
  }
  unsigned int run = part[t] - s;          // exclusive prefix of this segment
  #pragma unroll
  for (int j = 0; j < SEG; ++j) {
    unsigned int c = hist[base + j];
    offs[base + j] = run;
    run += c;
  }
}

__global__ __launch_bounds__(256) void scatter_kernel(const float* __restrict__ pos,
                                                      unsigned int* __restrict__ offs,
                                                      nfloat4* __restrict__ sorted, int B) {
  int i = blockIdx.x * 256 + threadIdx.x;
  if (i >= B) return;
  float x = pos[i*3], y = pos[i*3+1], z = pos[i*3+2];
  unsigned int slot = atomicAdd(&offs[cell_of(x, y, z)], 1u);
  nfloat4 v = {x, y, z, __int_as_float(i)};
  sorted[slot] = v;
}

// ---------------- main encode ----------------

// R4 structure (register results, ascending levels, one burst store) with the
// host-verified multiplier replacing the divide chain. __launch_bounds__(256,3)
// pins VGPR <= ~168 so the scheduler's gather-hoisting can't collapse
// occupancy (R7: unbounded -> 244 VGPR -> 8 waves/CU).
template <bool ALL_MUL>
__global__ __launch_bounds__(256, 3) void triplane_main(
    const nfloat4* __restrict__ sorted,
    const float* __restrict__ table,
    float* __restrict__ out,
    ResParams P, int B, int nwg)
{
  // XCD-chunked bijective swizzle: each XCD gets a contiguous chunk of the
  // spatially-sorted index space -> neighboring blocks share an L2.
  int wg = blockIdx.x;
  int q = nwg >> 3, r = nwg & 7;
  int xcd = wg & 7, idx = wg >> 3;
  int swz = (xcd < r) ? xcd * (q + 1) + idx : r * (q + 1) + (xcd - r) * q + idx;
  int t = swz * 256 + (int)threadIdx.x;
  if (t >= B) return;

  nfloat4 s = sorted[t];
  float x = s.x, y = s.y, z = s.z;
  int orig = __float_as_int(s.w);

  float uarr[3] = {x, y, z};
  float varr[3] = {y, z, x};

  float o0[LEVELS], o1[LEVELS];

  #pragma unroll
  for (int l = 0; l < LEVELS; ++l) {
    const float resm1 = (float)(P.res[l] - 1);

    float prod0 = 1.0f, prod1 = 1.0f;

    #pragma unroll
    for (int p = 0; p < 3; ++p) {
      // pos = u*(res-1) + 0.5 with separate mul/add roundings (no FMA) to
      // bit-match numpy at the floor() discontinuities.
      float pu = __fadd_rn(__fmul_rn(uarr[p], resm1), 0.5f);
      float pv = __fadd_rn(__fmul_rn(varr[p], resm1), 0.5f);
      float gu = floorf(pu), gv = floorf(pv);
      float fu = __fsub_rn(pu, gu);
      float fv = __fsub_rn(pv, gv);
      float gu1 = __fadd_rn(gu, 1.0f);
      float gv1 = __fadd_rn(gv, 1.0f);

      int cou0, cou1, cov0, cov1;
      if (ALL_MUL || ((P.mulmask >> l) & 1)) {
        // host-verified: trunc(c*m) == trunc((c/res)*2047) for ALL c in [0,res]
        const float m = P.mul[l];
        cou0 = (int)__fmul_rn(gu,  m);
        cou1 = (int)__fmul_rn(gu1, m);
        cov0 = (int)__fmul_rn(gv,  m);
        cov1 = (int)__fmul_rn(gv1, m);
      } else {
        const float fres = (float)P.res[l];
        cou0 = (int)(__fmul_rn(__fdiv_rn(gu,  fres), 2047.0f));
        cou1 = (int)(__fmul_rn(__fdiv_rn(gu1, fres), 2047.0f));
        cov0 = (int)(__fmul_rn(__fdiv_rn(gv,  fres), 2047.0f));
        cov1 = (int)(__fmul_rn(__fdiv_rn(gv1, fres), 2047.0f));
      }

      const float* plane = table + (size_t)p * (MAX_RES * MAX_RES * 2);

      const float2 f00 = *reinterpret_cast<const float2*>(plane + (size_t)(cou0 + (cov0 << 11)) * 2);
      const float2 f10 = *reinterpret_cast<const float2*>(plane + (size_t)(cou1 + (cov0 << 11)) * 2);
      const float2 f01 = *reinterpret_cast<const float2*>(plane + (size_t)(cou0 + (cov1 << 11)) * 2);
      const float2 f11 = *reinterpret_cast<const float2*>(plane + (size_t)(cou1 + (cov1 << 11)) * 2);

      float w00 = (1.0f - fu) * (1.0f - fv);
      float w10 = fu * (1.0f - fv);
      float w01 = (1.0f - fu) * fv;
      float w11 = fu * fv;

      float a0 = 0.0f, a1 = 0.0f;
      a0 += w00 * f00.x;  a1 += w00 * f00.y;
      a0 += w10 * f10.x;  a1 += w10 * f10.y;
      a0 += w01 * f01.x;  a1 += w01 * f01.y;
      a0 += w11 * f11.x;  a1 += w11 * f11.y;

      prod0 *= a0;
      prod1 *= a1;
    }

    o0[l] = prod0;
    o1[l] = prod1;
  }

  // 128 B contiguous per thread, all stores back-to-back so L2 merges the
  // full line (staggered partial-line writes caused RFO amplification).
  nfloat4* base = reinterpret_cast<nfloat4*>(out + (size_t)orig * 32);
  #pragma unroll
  for (int k = 0; k < 4; ++k) {
    nfloat4 v0 = {o0[k*4+0], o0[k*4+1], o0[k*4+2], o0[k*4+3]};
    nfloat4 v1 = {o1[k*4+0], o1[k*4+1], o1[k*4+2], o1[k*4+3]};
    base[k] = v0;
    base[4 + k] = v1;
  }
}

extern "C" void kernel_launch(void* const* d_in, const int* in_sizes, int n_in,
                              void* d_out, int out_size, void* d_ws, size_t ws_size,
                              hipStream_t stream) {
  const float* positions = (const float*)d_in[0];
  const float* table     = (const float*)d_in[1];
  float* out             = (float*)d_out;
  int B = in_sizes[0] / 3;

  // Reproduce the Python host-side res computation bit-exactly (same libm),
  // then exhaustively verify a per-level multiplier that replaces the
  // divide+mul index computation with a single fmul (exact where verified).
  ResParams P;
  P.mulmask = 0;
  const double LOG_B = log(2048.0 / 16.0) / (double)(LEVELS - 1);
  for (int l = 0; l < LEVELS; ++l) {
    double scale = 16.0 * exp((double)l * LOG_B) - 1.0;
    int res = (int)ceil(scale) + 1;
    P.res[l] = res;
    P.mul[l] = 0.0f;
    float fres = (float)res;
    float m0 = (float)(2047.0 / (double)res);
    float cands[3] = { m0, nextafterf(m0, 3.4e38f), nextafterf(m0, 0.0f) };
    for (int ci = 0; ci < 3; ++ci) {
      bool ok = true;
      for (int c = 0; c <= res; ++c) {
        volatile float cf = (float)c;
        volatile float qq = cf / fres;            // IEEE RN divide (matches __fdiv_rn)
        volatile float rr = qq * 2047.0f;         // IEEE RN mul    (matches __fmul_rn)
        volatile float rc = cf * cands[ci];
        if ((int)rr != (int)rc) { ok = false; break; }
      }
      if (ok) { P.mul[l] = cands[ci]; P.mulmask |= (1 << l); break; }
    }
  }

  int nwg = (B + 255) / 256;

  // workspace layout (bytes)
  size_t off_hist   = 0;
  size_t off_offs   = off_hist + (size_t)NCELLS * 4;
  size_t off_sorted = off_offs + (size_t)NCELLS * 4;
  size_t need       = off_sorted + (size_t)B * 16;

  if (ws_size >= need) {
    unsigned int* hist = (unsigned int*)((char*)d_ws + off_hist);
    unsigned int* offs = (unsigned int*)((char*)d_ws + off_offs);
    nfloat4*      srt  = (nfloat4*)((char*)d_ws + off_sorted);

    hipLaunchKernelGGL(zero_hist, dim3((NCELLS + 255) / 256), dim3(256), 0, stream, hist);
    hipLaunchKernelGGL(keys_hist, dim3(nwg), dim3(256), 0, stream, positions, hist, B);
    hipLaunchKernelGGL(scan_kernel, dim3(1), dim3(1024), 0, stream, hist, offs);
    hipLaunchKernelGGL(scatter_kernel, dim3(nwg), dim3(256), 0, stream, positions, offs, srt, B);
    if (P.mulmask == 0xFFFF) {
      hipLaunchKernelGGL((triplane_main<true>), dim3(nwg), dim3(256), 0, stream,
                         srt, table, out, P, B, nwg);
    } else {
      hipLaunchKernelGGL((triplane_main<false>), dim3(nwg), dim3(256), 0, stream,
                         srt, table, out, P, B, nwg);
    }
  }
}

// Round 10
// 444.777 us; speedup vs baseline: 1.0736x; 1.0736x over previous
//
#include <hip/hip_runtime.h>
#include <math.h>

#define LEVELS 16
#define MAX_RES 2048
#define NCELL_BITS 5
#define NCELLS (1 << (3 * NCELL_BITS))   // 32768 cells (32^3), ~32 points/cell

typedef float nfloat4 __attribute__((ext_vector_type(4)));

struct ResParams { int res[LEVELS]; };

// ---------------- sort pipeline ----------------

__global__ __launch_bounds__(256) void zero_hist(unsigned int* hist) {
  int i = blockIdx.x * 256 + threadIdx.x;
  if (i < NCELLS) hist[i] = 0u;
}

__device__ __forceinline__ unsigned int morton5(int cx, int cy, int cz) {
  unsigned int k = 0;
  #pragma unroll
  for (int b = 0; b < NCELL_BITS; ++b)
    k |= (((cx >> b) & 1) << (3 * b)) | (((cy >> b) & 1) << (3 * b + 1)) |
         (((cz >> b) & 1) << (3 * b + 2));
  return k;
}

__device__ __forceinline__ unsigned int cell_of(float x, float y, float z) {
  int cx = min(31, max(0, (int)(x * 32.0f)));
  int cy = min(31, max(0, (int)(y * 32.0f)));
  int cz = min(31, max(0, (int)(z * 32.0f)));
  return morton5(cx, cy, cz);
}

__global__ __launch_bounds__(256) void keys_hist(const float* __restrict__ pos,
                                                 unsigned int* __restrict__ hist, int B) {
  int i = blockIdx.x * 256 + threadIdx.x;
  if (i >= B) return;
  atomicAdd(&hist[cell_of(pos[i*3], pos[i*3+1], pos[i*3+2])], 1u);
}

__global__ __launch_bounds__(1024) void scan_kernel(const unsigned int* __restrict__ hist,
                                                    unsigned int* __restrict__ offs) {
  __shared__ unsigned int part[1024];
  const int SEG = NCELLS / 1024;          // 32
  int t = threadIdx.x;
  int base = t * SEG;
  unsigned int s = 0;
  #pragma unroll
  for (int j = 0; j < SEG; ++j) s += hist[base + j];
  part[t] = s;
  __syncthreads();
  for (int off = 1; off < 1024; off <<= 1) {
    unsigned int v = (t >= off) ? part[t - off] : 0u;
    __syncthreads();
    part[t] += v;
    __syncthreads();
  }
  unsigned int run = part[t] - s;          // exclusive prefix of this segment
  #pragma unroll
  for (int j = 0; j < SEG; ++j) {
    unsigned int c = hist[base + j];
    offs[base + j] = run;
    run += c;
  }
}

__global__ __launch_bounds__(256) void scatter_kernel(const float* __restrict__ pos,
                                                      unsigned int* __restrict__ offs,
                                                      nfloat4* __restrict__ sorted, int B) {
  int i = blockIdx.x * 256 + threadIdx.x;
  if (i >= B) return;
  float x = pos[i*3], y = pos[i*3+1], z = pos[i*3+2];
  unsigned int slot = atomicAdd(&offs[cell_of(x, y, z)], 1u);
  nfloat4 v = {x, y, z, __int_as_float(i)};
  sorted[slot] = v;
}

// ---------------- main encode ----------------

// Exact R4 structure: register results, ascending levels, burst store,
// IEEE divide index math, no min-wave bound. The div chains happen to force
// the compiler into a tight ~68-VGPR schedule that measured fastest (354us);
// every "improved" variant (mul, LDS sink, pinned bounds) was slower.
// Single instantiation: no co-compiled template variants perturbing codegen.
__global__ __launch_bounds__(256) void triplane_main(
    const nfloat4* __restrict__ sorted,
    const float* __restrict__ table,
    float* __restrict__ out,
    ResParams P, int B, int nwg)
{
  // XCD-chunked bijective swizzle: each XCD gets a contiguous chunk of the
  // spatially-sorted index space -> neighboring blocks share an L2.
  int wg = blockIdx.x;
  int q = nwg >> 3, r = nwg & 7;
  int xcd = wg & 7, idx = wg >> 3;
  int swz = (xcd < r) ? xcd * (q + 1) + idx : r * (q + 1) + (xcd - r) * q + idx;
  int t = swz * 256 + (int)threadIdx.x;
  if (t >= B) return;

  nfloat4 s = sorted[t];
  float x = s.x, y = s.y, z = s.z;
  int orig = __float_as_int(s.w);

  float uarr[3] = {x, y, z};
  float varr[3] = {y, z, x};

  float o0[LEVELS], o1[LEVELS];

  #pragma unroll
  for (int l = 0; l < LEVELS; ++l) {
    const int   res   = P.res[l];
    const float resm1 = (float)(res - 1);
    const float fres  = (float)res;

    float prod0 = 1.0f, prod1 = 1.0f;

    #pragma unroll
    for (int p = 0; p < 3; ++p) {
      // pos = u*(res-1) + 0.5 with separate mul/add roundings (no FMA) to
      // bit-match numpy at the floor() discontinuities.
      float pu = __fadd_rn(__fmul_rn(uarr[p], resm1), 0.5f);
      float pv = __fadd_rn(__fmul_rn(varr[p], resm1), 0.5f);
      float gu = floorf(pu), gv = floorf(pv);
      float fu = __fsub_rn(pu, gu);
      float fv = __fsub_rn(pv, gv);
      float gu1 = __fadd_rn(gu, 1.0f);
      float gv1 = __fadd_rn(gv, 1.0f);

      // c_ori = trunc((c / res) * 2047) -- IEEE div + mul, truncate
      int cou0 = (int)(__fmul_rn(__fdiv_rn(gu,  fres), 2047.0f));
      int cou1 = (int)(__fmul_rn(__fdiv_rn(gu1, fres), 2047.0f));
      int cov0 = (int)(__fmul_rn(__fdiv_rn(gv,  fres), 2047.0f));
      int cov1 = (int)(__fmul_rn(__fdiv_rn(gv1, fres), 2047.0f));

      const float* plane = table + (size_t)p * (MAX_RES * MAX_RES * 2);

      const float2 f00 = *reinterpret_cast<const float2*>(plane + (size_t)(cou0 + (cov0 << 11)) * 2);
      const float2 f10 = *reinterpret_cast<const float2*>(plane + (size_t)(cou1 + (cov0 << 11)) * 2);
      const float2 f01 = *reinterpret_cast<const float2*>(plane + (size_t)(cou0 + (cov1 << 11)) * 2);
      const float2 f11 = *reinterpret_cast<const float2*>(plane + (size_t)(cou1 + (cov1 << 11)) * 2);

      float w00 = (1.0f - fu) * (1.0f - fv);
      float w10 = fu * (1.0f - fv);
      float w01 = (1.0f - fu) * fv;
      float w11 = fu * fv;

      float a0 = 0.0f, a1 = 0.0f;
      a0 += w00 * f00.x;  a1 += w00 * f00.y;
      a0 += w10 * f10.x;  a1 += w10 * f10.y;
      a0 += w01 * f01.x;  a1 += w01 * f01.y;
      a0 += w11 * f11.x;  a1 += w11 * f11.y;

      prod0 *= a0;
      prod1 *= a1;
    }

    o0[l] = prod0;
    o1[l] = prod1;
  }

  // 128 B contiguous per thread, all stores back-to-back so L2 merges the
  // full line (staggered partial-line writes caused RFO amplification).
  nfloat4* base = reinterpret_cast<nfloat4*>(out + (size_t)orig * 32);
  #pragma unroll
  for (int k = 0; k < 4; ++k) {
    nfloat4 v0 = {o0[k*4+0], o0[k*4+1], o0[k*4+2], o0[k*4+3]};
    nfloat4 v1 = {o1[k*4+0], o1[k*4+1], o1[k*4+2], o1[k*4+3]};
    base[k] = v0;
    base[4 + k] = v1;
  }
}

extern "C" void kernel_launch(void* const* d_in, const int* in_sizes, int n_in,
                              void* d_out, int out_size, void* d_ws, size_t ws_size,
                              hipStream_t stream) {
  const float* positions = (const float*)d_in[0];
  const float* table     = (const float*)d_in[1];
  float* out             = (float*)d_out;
  int B = in_sizes[0] / 3;

  // Reproduce the Python host-side res computation bit-exactly (same libm).
  ResParams P;
  const double LOG_B = log(2048.0 / 16.0) / (double)(LEVELS - 1);
  for (int l = 0; l < LEVELS; ++l) {
    double scale = 16.0 * exp((double)l * LOG_B) - 1.0;
    P.res[l] = (int)ceil(scale) + 1;
  }

  int nwg = (B + 255) / 256;

  // workspace layout (bytes)
  size_t off_hist   = 0;
  size_t off_offs   = off_hist + (size_t)NCELLS * 4;
  size_t off_sorted = off_offs + (size_t)NCELLS * 4;
  size_t need       = off_sorted + (size_t)B * 16;

  if (ws_size >= need) {
    unsigned int* hist = (unsigned int*)((char*)d_ws + off_hist);
    unsigned int* offs = (unsigned int*)((char*)d_ws + off_offs);
    nfloat4*      srt  = (nfloat4*)((char*)d_ws + off_sorted);

    hipLaunchKernelGGL(zero_hist, dim3((NCELLS + 255) / 256), dim3(256), 0, stream, hist);
    hipLaunchKernelGGL(keys_hist, dim3(nwg), dim3(256), 0, stream, positions, hist, B);
    hipLaunchKernelGGL(scan_kernel, dim3(1), dim3(1024), 0, stream, hist, offs);
    hipLaunchKernelGGL(scatter_kernel, dim3(nwg), dim3(256), 0, stream, positions, offs, srt, B);
    hipLaunchKernelGGL(triplane_main, dim3(nwg), dim3(256), 0, stream,
                       srt, table, out, P, B, nwg);
  }
}